// Round 22
// baseline (38.714 us; speedup 1.0000x reference)
//
#include <hip/hip_runtime.h>

#define BB 32
#define NN 512
#define PP 128
#define MM (BB * NN)  // 16384 rows

typedef unsigned int u32;
typedef unsigned short u16;

typedef __attribute__((ext_vector_type(8))) short short8v;  // 8 bf16 (4 VGPR)
typedef __attribute__((ext_vector_type(4))) float f32x4;

// ---- ws layout (r21 verbatim) ----
#define UVB_OFF (16 * MM)               // u[128], v[128], bias[128]
#define MUTHI_OFF ((size_t)20971520)    // u16 [BB][PP][NN] = 4 MB (muT hi)
#define W2T_OFF ((size_t)29360128)      // u16 [PP][PP] = 32 KB (W2T[p][q]=bf16(W2[q][p]))

__device__ inline u32 bf16rne(float f) {
    u32 u = __float_as_uint(f);
    return (u + 0x7FFFu + ((u >> 16) & 1u)) >> 16;
}

// aux (r21 verbatim): bid<256: mu transpose -> muT bf16; 256: uv+bias;
// 257: W2T bf16.
__global__ __launch_bounds__(256) void k_aux(
    const float* __restrict__ mu, const float* __restrict__ W2,
    const float* __restrict__ t4, const float* __restrict__ W3,
    const float* __restrict__ b1, const float* __restrict__ b2,
    const float* __restrict__ b3, float* __restrict__ uvb,
    u16* __restrict__ muthi, u16* __restrict__ w2t) {
    __shared__ float tile[64][132];
    __shared__ float su[2][PP], sv[2][PP];
    int bid = blockIdx.x;
    int t = threadIdx.x;
    if (bid < 256) {
        int b = bid >> 3, i0 = (bid & 7) * 64;
        const float4* mu4 = (const float4*)(mu + ((size_t)b * NN + i0) * PP);
#pragma unroll
        for (int s = 0; s < 8; ++s) {
            int n = s * 256 + t;
            int ii = n >> 5, c4 = n & 31;
            float4 v = mu4[ii * 32 + c4];
            *(float4*)&tile[ii][c4 * 4] = v;
        }
        __syncthreads();
        int p = t >> 1, half = t & 1;
        u32* hdst = (u32*)(muthi + ((size_t)b * PP + p) * NN + i0 + half * 32);
#pragma unroll
        for (int e2 = 0; e2 < 16; ++e2) {
            float v0 = tile[half * 32 + 2 * e2][p];
            float v1 = tile[half * 32 + 2 * e2 + 1][p];
            hdst[e2] = bf16rne(v0) | (bf16rne(v1) << 16);
        }
    } else if (bid == 256) {
        int p = t & 127, h = t >> 7;
        float u = 0.f, v = 0.f;
#pragma unroll 8
        for (int q = h * 64; q < h * 64 + 64; ++q) {
            float tt = t4[q];
            float w = W3[q * PP + p];
            u += fmaxf(tt, 0.f) * w;
            v += fmaxf(-tt, 0.f) * w;
        }
        su[h][p] = u;
        sv[h][p] = v;
        __syncthreads();
        if (t < PP) {
            uvb[p] = su[0][p] + su[1][p];
            uvb[PP + p] = sv[0][p] + sv[1][p];
            uvb[2 * PP + p] = b1[p] + b2[p] + b3[p];
        }
    } else {
#pragma unroll 4
        for (int c = 0; c < 64; ++c) {
            int n = c * 256 + t;
            int q = n >> 7, pp = n & 127;
            w2t[pp * PP + q] = (u16)bf16rne(W2[q * PP + pp]);
        }
    }
}

// fused (r21 structure, w2L deleted): phase-2 B-fragment loaded DIRECT from
// global w2t (32 KB, L1/L2-hot). Pool shrinks 48->23 KB; ahiL/aloL alias the
// dead phase-1 region. Occupancy 2 -> 4 blocks/CU (wave cap).
// 512 blocks = 32 b x 16 j-tiles(32); 512 thr = 8 waves; wave w: p-slice 16.
__global__ __launch_bounds__(512) void k_fused(
    const float* __restrict__ adjF, const float* __restrict__ weight,
    const u16* __restrict__ muthi, const u16* __restrict__ w2t,
    const float* __restrict__ x, const float* __restrict__ W1,
    const float* __restrict__ uvb, float* __restrict__ out) {
    __shared__ __align__(16) u16 pool[11520];  // 22.5 KB
    // phase1 carve: adjL [32][72] @0; mhiL [128][72] @2304 (ends 11520)
    u16* adjL = pool;
    u16* mhiL = pool + 2304;
    // phase2 carve (aliases phase1, barrier-separated):
    // ahiL [32][128 swz] @0; aloL @4096
    u16* ahiL = pool;
    u16* aloL = pool + 4096;
    __shared__ float psP[16][33], ngP[16][33];  // padded
    __shared__ float psF[32], ngF[32];

    int bid = blockIdx.x;
    int vbid = ((bid & 7) << 6) | (bid >> 3);  // XCD chunking (bijective)
    int b = vbid >> 4;
    int j0 = (vbid & 15) * 32;
    int tx = threadIdx.x, lane = tx & 63, w = tx >> 6;

    const float* adjrow = adjF + ((size_t)b * NN + j0) * NN;  // [j][i] rows
    const float* adjcol = adjF + (size_t)b * NN * NN + j0;     // [i][j] cols
    const float* wcol = weight + (size_t)b * NN * NN + j0;     // [i][j] cols
    const u16* mhG = muthi + (size_t)b * PP * NN;

    // staging maps (r21 verbatim)
    int sj = tx >> 4, sk = (tx & 15) * 4;   // adj: row sj, float4 col sk
    int sp = tx >> 2, sk2 = (tx & 3) * 16;  // mu: row sp, 2x uint4 col sk2
    const float* adjsrc = adjrow + (size_t)sj * NN + sk;
    const u16* mhsrc = mhG + (size_t)sp * NN + sk2;

    // pos/neg mapping (r21 verbatim): jw = tx&31, kgrp = tx>>5
    int jw = tx & 31, kgrp = tx >> 5;
    float ps = 0.f, ng = 0.f;

    f32x4 acc[2];  // [jt]; wave w owns p-slice [16w, 16w+16)
    acc[0] = (f32x4){0.f, 0.f, 0.f, 0.f};
    acc[1] = (f32x4){0.f, 0.f, 0.f, 0.f};

    // ---- prologue: issue step-0 loads into registers ----
    float4 fA = *(const float4*)(adjsrc);
    uint4 h0 = *(const uint4*)(mhsrc);
    uint4 h1 = *(const uint4*)(mhsrc + 8);

    for (int step = 0; step < 8; ++step) {
        int k0 = step * 64;
        {  // write staged regs -> LDS (adj: 0/1 -> bf16 exact)
            uint2 o;
            o.x = (fA.x != 0.f ? 0x3F80u : 0u) | (fA.y != 0.f ? 0x3F800000u : 0u);
            o.y = (fA.z != 0.f ? 0x3F80u : 0u) | (fA.w != 0.f ? 0x3F800000u : 0u);
            *(uint2*)&adjL[sj * 72 + sk] = o;
            *(uint4*)&mhiL[sp * 72 + sk2] = h0;
            *(uint4*)&mhiL[sp * 72 + sk2 + 8] = h1;
        }
        {  // inline pos/neg (r21 verbatim): 4 i's this step
#pragma unroll
            for (int kk = 0; kk < 4; ++kk) {
                size_t off = (size_t)(k0 + kgrp * 4 + kk) * NN + jw;
                float wv = wcol[off];
                float av = adjcol[off];  // exactly 0.0 or 1.0
                ps += fmaxf(wv, 0.f) * av;
                ng += fmaxf(-wv, 0.f) * av;
            }
        }
        __syncthreads();
        // ---- issue NEXT-step global loads (land during MFMA + barriers) ----
        if (step < 7) {
            int kn = k0 + 64;
            fA = *(const float4*)(adjsrc + kn);
            h0 = *(const uint4*)(mhsrc + kn);
            h1 = *(const uint4*)(mhsrc + kn + 8);
        }
        // ---- MFMA current step from LDS (r21 verbatim: 4 MFMA/wave) ----
#pragma unroll
        for (int ks = 0; ks < 2; ++ks) {
            int kb = ks * 32 + (lane >> 4) * 8;
            short8v afr0 = *(const short8v*)&adjL[(0 + (lane & 15)) * 72 + kb];
            short8v afr1 = *(const short8v*)&adjL[(16 + (lane & 15)) * 72 + kb];
            int prow = w * 16 + (lane & 15);
            short8v bh = *(const short8v*)&mhiL[prow * 72 + kb];
            acc[0] = __builtin_amdgcn_mfma_f32_16x16x32_bf16(afr0, bh, acc[0], 0, 0, 0);
            acc[1] = __builtin_amdgcn_mfma_f32_16x16x32_bf16(afr1, bh, acc[1], 0, 0, 0);
        }
        __syncthreads();
    }

    // pos/neg partials -> LDS; acc -> agg hi/lo (XOR-swz) into the now-dead
    // phase-1 region (last loop barrier separates). No W2 staging.
    psP[kgrp][jw] = ps;
    ngP[kgrp][jw] = ng;
    {
#pragma unroll
        for (int jt = 0; jt < 2; ++jt)
#pragma unroll
            for (int r = 0; r < 4; ++r) {
                int j = jt * 16 + (lane >> 4) * 4 + r;
                int q = w * 16 + (lane & 15);
                float v = acc[jt][r];
                u32 h = bf16rne(v);
                float lf = v - __uint_as_float(h << 16);
                int qs = q ^ ((j & 7) << 3);
                ahiL[j * 128 + qs] = (u16)h;
                aloL[j * 128 + qs] = (u16)bf16rne(lf);
            }
    }
    __syncthreads();

    // final pos/neg reduce (32 threads)
    if (tx < 32) {
        float P = 0.f, Ng = 0.f;
#pragma unroll
        for (int g = 0; g < 16; ++g) {
            P += psP[g][tx];
            Ng += ngP[g][tx];
        }
        psF[tx] = P;
        ngF[tx] = Ng;
    }

    // phase 2: D2[j][p'] = sum_q agg[j][q] * W2[q][p']; B direct from global
    f32x4 acc2[2];
    acc2[0] = (f32x4){0.f, 0.f, 0.f, 0.f};
    acc2[1] = (f32x4){0.f, 0.f, 0.f, 0.f};
    {
        int prow = w * 16 + (lane & 15);
        const u16* w2row = w2t + prow * PP;
#pragma unroll
        for (int ks = 0; ks < 4; ++ks) {
            int kb = ks * 32 + (lane >> 4) * 8;
            short8v bfr = *(const short8v*)(w2row + kb);  // L1/L2-hot, 16B
#pragma unroll
            for (int jt = 0; jt < 2; ++jt) {
                int jrow = jt * 16 + (lane & 15);
                short8v ah = *(const short8v*)&ahiL[jrow * 128 + (kb ^ ((jrow & 7) << 3))];
                short8v al = *(const short8v*)&aloL[jrow * 128 + (kb ^ ((jrow & 7) << 3))];
                acc2[jt] = __builtin_amdgcn_mfma_f32_16x16x32_bf16(ah, bfr, acc2[jt], 0, 0, 0);
                acc2[jt] = __builtin_amdgcn_mfma_f32_16x16x32_bf16(al, bfr, acc2[jt], 0, 0, 0);
            }
        }
    }
    __syncthreads();  // psF/ngF visible to all

    // epilogue (r21 verbatim): wave w owns p' in [16w, 16w+16)
    int pp = w * 16 + (lane & 15);
    float u_ = uvb[pp];
    float v_ = uvb[PP + pp];
    float bb_ = uvb[2 * PP + pp];
    float w1_ = W1[pp];
    int row0 = b * NN + j0;
#pragma unroll
    for (int jt = 0; jt < 2; ++jt)
#pragma unroll
        for (int r = 0; r < 4; ++r) {
            int jloc = jt * 16 + (lane >> 4) * 4 + r;
            int row = row0 + jloc;
            float xs = x[row];
            float o = acc2[jt][r] + xs * w1_ + psF[jloc] * u_ + ngF[jloc] * v_ + bb_;
            out[(size_t)row * PP + pp] = fmaxf(o, 0.f);
        }
}

extern "C" void kernel_launch(void* const* d_in, const int* in_sizes, int n_in,
                              void* d_out, int out_size, void* d_ws, size_t ws_size,
                              hipStream_t stream) {
    const float* x      = (const float*)d_in[0];
    const float* mu     = (const float*)d_in[1];
    const float* weight = (const float*)d_in[2];
    const float* adj    = (const float*)d_in[3];
    const float* W1     = (const float*)d_in[4];
    const float* b1     = (const float*)d_in[5];
    const float* W2     = (const float*)d_in[6];
    const float* b2     = (const float*)d_in[7];
    const float* W3     = (const float*)d_in[8];
    const float* b3     = (const float*)d_in[9];
    const float* theta4 = (const float*)d_in[10];
    float* out = (float*)d_out;

    float* ws  = (float*)d_ws;
    float* uvb = ws + UVB_OFF;
    u16* muthi = (u16*)((char*)d_ws + MUTHI_OFF);
    u16* w2t   = (u16*)((char*)d_ws + W2T_OFF);

    k_aux<<<258, 256, 0, stream>>>(mu, W2, theta4, W3, b1, b2, b3, uvb,
                                   muthi, w2t);

    k_fused<<<512, 512, 0, stream>>>(adj, weight, muthi, w2t, x, W1,
                                     uvb, out);
}

// Round 23
// 37.389 us; speedup vs baseline: 1.0354x; 1.0354x over previous
//
#include <hip/hip_runtime.h>

#define BB 32
#define NN 512
#define PP 128
#define MM (BB * NN)  // 16384 rows

typedef unsigned int u32;
typedef unsigned short u16;

typedef __attribute__((ext_vector_type(8))) short short8v;  // 8 bf16 (4 VGPR)
typedef __attribute__((ext_vector_type(4))) float f32x4;

// ---- ws layout (r21 verbatim) ----
#define UVB_OFF (16 * MM)               // u[128], v[128], bias[128]
#define MUTHI_OFF ((size_t)20971520)    // u16 [BB][PP][NN] = 4 MB (muT hi)
#define W2T_OFF ((size_t)29360128)      // u16 [PP][PP] = 32 KB (W2T[p][q]=bf16(W2[q][p]))

__device__ inline u32 bf16rne(float f) {
    u32 u = __float_as_uint(f);
    return (u + 0x7FFFu + ((u >> 16) & 1u)) >> 16;
}

// aux (r21 verbatim): bid<256: mu transpose -> muT bf16; 256: uv+bias;
// 257: W2T bf16.
__global__ __launch_bounds__(256) void k_aux(
    const float* __restrict__ mu, const float* __restrict__ W2,
    const float* __restrict__ t4, const float* __restrict__ W3,
    const float* __restrict__ b1, const float* __restrict__ b2,
    const float* __restrict__ b3, float* __restrict__ uvb,
    u16* __restrict__ muthi, u16* __restrict__ w2t) {
    __shared__ float tile[64][132];
    __shared__ float su[2][PP], sv[2][PP];
    int bid = blockIdx.x;
    int t = threadIdx.x;
    if (bid < 256) {
        int b = bid >> 3, i0 = (bid & 7) * 64;
        const float4* mu4 = (const float4*)(mu + ((size_t)b * NN + i0) * PP);
#pragma unroll
        for (int s = 0; s < 8; ++s) {
            int n = s * 256 + t;
            int ii = n >> 5, c4 = n & 31;
            float4 v = mu4[ii * 32 + c4];
            *(float4*)&tile[ii][c4 * 4] = v;
        }
        __syncthreads();
        int p = t >> 1, half = t & 1;
        u32* hdst = (u32*)(muthi + ((size_t)b * PP + p) * NN + i0 + half * 32);
#pragma unroll
        for (int e2 = 0; e2 < 16; ++e2) {
            float v0 = tile[half * 32 + 2 * e2][p];
            float v1 = tile[half * 32 + 2 * e2 + 1][p];
            hdst[e2] = bf16rne(v0) | (bf16rne(v1) << 16);
        }
    } else if (bid == 256) {
        int p = t & 127, h = t >> 7;
        float u = 0.f, v = 0.f;
#pragma unroll 8
        for (int q = h * 64; q < h * 64 + 64; ++q) {
            float tt = t4[q];
            float w = W3[q * PP + p];
            u += fmaxf(tt, 0.f) * w;
            v += fmaxf(-tt, 0.f) * w;
        }
        su[h][p] = u;
        sv[h][p] = v;
        __syncthreads();
        if (t < PP) {
            uvb[p] = su[0][p] + su[1][p];
            uvb[PP + p] = sv[0][p] + sv[1][p];
            uvb[2 * PP + p] = b1[p] + b2[p] + b3[p];
        }
    } else {
#pragma unroll 4
        for (int c = 0; c < 64; ++c) {
            int n = c * 256 + t;
            int q = n >> 7, pp = n & 127;
            w2t[pp * PP + q] = (u16)bf16rne(W2[q * PP + pp]);
        }
    }
}

// fused (r21 structure + posneg prefetch): ALL step-loop global loads are now
// one-step-ahead register-rotated (stage + posneg).
// 512 blocks = 32 b x 16 j-tiles(32); 512 thr = 8 waves; wave w: p-slice 16.
__global__ __launch_bounds__(512) void k_fused(
    const float* __restrict__ adjF, const float* __restrict__ weight,
    const u16* __restrict__ muthi, const u16* __restrict__ w2t,
    const float* __restrict__ x, const float* __restrict__ W1,
    const float* __restrict__ uvb, float* __restrict__ out) {
    __shared__ __align__(16) u16 pool[24576];  // 48 KB
    // phase1 carve: adjL [32][72] @0; mhiL [128][72] @2304
    u16* adjL = pool;
    u16* mhiL = pool + 2304;
    // phase2 carve (aliases, barrier-separated): w2L [128][128 swz] @0;
    // ahiL [32][128 swz] @16384; aloL @20480
    u16* w2L = pool;
    u16* ahiL = pool + 16384;
    u16* aloL = pool + 20480;
    __shared__ float psP[16][33], ngP[16][33];  // padded
    __shared__ float psF[32], ngF[32];

    int bid = blockIdx.x;
    int vbid = ((bid & 7) << 6) | (bid >> 3);  // XCD chunking (bijective)
    int b = vbid >> 4;
    int j0 = (vbid & 15) * 32;
    int tx = threadIdx.x, lane = tx & 63, w = tx >> 6;

    const float* adjrow = adjF + ((size_t)b * NN + j0) * NN;  // [j][i] rows
    const float* adjcol = adjF + (size_t)b * NN * NN + j0;     // [i][j] cols
    const float* wcol = weight + (size_t)b * NN * NN + j0;     // [i][j] cols
    const u16* mhG = muthi + (size_t)b * PP * NN;

    // staging maps (r21 verbatim)
    int sj = tx >> 4, sk = (tx & 15) * 4;   // adj: row sj, float4 col sk
    int sp = tx >> 2, sk2 = (tx & 3) * 16;  // mu: row sp, 2x uint4 col sk2
    const float* adjsrc = adjrow + (size_t)sj * NN + sk;
    const u16* mhsrc = mhG + (size_t)sp * NN + sk2;

    // pos/neg mapping (r21 verbatim): jw = tx&31, kgrp = tx>>5
    int jw = tx & 31, kgrp = tx >> 5;
    float ps = 0.f, ng = 0.f;

    f32x4 acc[2];  // [jt]; wave w owns p-slice [16w, 16w+16)
    acc[0] = (f32x4){0.f, 0.f, 0.f, 0.f};
    acc[1] = (f32x4){0.f, 0.f, 0.f, 0.f};

    // ---- prologue: issue step-0 loads into registers (stage + posneg) ----
    float4 fA = *(const float4*)(adjsrc);
    uint4 h0 = *(const uint4*)(mhsrc);
    uint4 h1 = *(const uint4*)(mhsrc + 8);
    float pwr[4], par[4];
#pragma unroll
    for (int kk = 0; kk < 4; ++kk) {
        size_t off = (size_t)(kgrp * 4 + kk) * NN + jw;
        pwr[kk] = wcol[off];
        par[kk] = adjcol[off];
    }

    for (int step = 0; step < 8; ++step) {
        int k0 = step * 64;
        {  // write staged regs -> LDS (adj: 0/1 -> bf16 exact)
            uint2 o;
            o.x = (fA.x != 0.f ? 0x3F80u : 0u) | (fA.y != 0.f ? 0x3F800000u : 0u);
            o.y = (fA.z != 0.f ? 0x3F80u : 0u) | (fA.w != 0.f ? 0x3F800000u : 0u);
            *(uint2*)&adjL[sj * 72 + sk] = o;
            *(uint4*)&mhiL[sp * 72 + sk2] = h0;
            *(uint4*)&mhiL[sp * 72 + sk2 + 8] = h1;
        }
        {  // accumulate CURRENT posneg registers (register-only math)
#pragma unroll
            for (int kk = 0; kk < 4; ++kk) {
                ps += fmaxf(pwr[kk], 0.f) * par[kk];
                ng += fmaxf(-pwr[kk], 0.f) * par[kk];
            }
        }
        __syncthreads();
        // ---- issue NEXT-step global loads (land during MFMA + barriers) ----
        if (step < 7) {
            int kn = k0 + 64;
            fA = *(const float4*)(adjsrc + kn);
            h0 = *(const uint4*)(mhsrc + kn);
            h1 = *(const uint4*)(mhsrc + kn + 8);
#pragma unroll
            for (int kk = 0; kk < 4; ++kk) {
                size_t off = (size_t)(kn + kgrp * 4 + kk) * NN + jw;
                pwr[kk] = wcol[off];
                par[kk] = adjcol[off];
            }
        }
        // ---- MFMA current step from LDS (r21 verbatim: 4 MFMA/wave) ----
#pragma unroll
        for (int ks = 0; ks < 2; ++ks) {
            int kb = ks * 32 + (lane >> 4) * 8;
            short8v afr0 = *(const short8v*)&adjL[(0 + (lane & 15)) * 72 + kb];
            short8v afr1 = *(const short8v*)&adjL[(16 + (lane & 15)) * 72 + kb];
            int prow = w * 16 + (lane & 15);
            short8v bh = *(const short8v*)&mhiL[prow * 72 + kb];
            acc[0] = __builtin_amdgcn_mfma_f32_16x16x32_bf16(afr0, bh, acc[0], 0, 0, 0);
            acc[1] = __builtin_amdgcn_mfma_f32_16x16x32_bf16(afr1, bh, acc[1], 0, 0, 0);
        }
        __syncthreads();
    }

    // pos/neg partials -> LDS; acc -> agg hi/lo (XOR-swz); stage W2T (r21 verbatim)
    psP[kgrp][jw] = ps;
    ngP[kgrp][jw] = ng;
    {
#pragma unroll
        for (int jt = 0; jt < 2; ++jt)
#pragma unroll
            for (int r = 0; r < 4; ++r) {
                int j = jt * 16 + (lane >> 4) * 4 + r;
                int q = w * 16 + (lane & 15);
                float v = acc[jt][r];
                u32 h = bf16rne(v);
                float lf = v - __uint_as_float(h << 16);
                int qs = q ^ ((j & 7) << 3);
                ahiL[j * 128 + qs] = (u16)h;
                aloL[j * 128 + qs] = (u16)bf16rne(lf);
            }
        int p = tx >> 2, c4 = tx & 3;
#pragma unroll
        for (int c = 0; c < 4; ++c) {
            int cc = c4 * 4 + c;
            int q8 = (cc * 8) ^ ((p & 7) << 3);
            *(uint4*)&w2L[p * 128 + q8] = *(const uint4*)(w2t + p * PP + cc * 8);
        }
    }
    __syncthreads();

    // final pos/neg reduce (32 threads)
    if (tx < 32) {
        float P = 0.f, Ng = 0.f;
#pragma unroll
        for (int g = 0; g < 16; ++g) {
            P += psP[g][tx];
            Ng += ngP[g][tx];
        }
        psF[tx] = P;
        ngF[tx] = Ng;
    }

    // phase 2 (r21 verbatim): D2[j][p'] = sum_q agg[j][q] * W2[q][p']
    f32x4 acc2[2];
    acc2[0] = (f32x4){0.f, 0.f, 0.f, 0.f};
    acc2[1] = (f32x4){0.f, 0.f, 0.f, 0.f};
#pragma unroll
    for (int ks = 0; ks < 4; ++ks) {
        int kb = ks * 32 + (lane >> 4) * 8;
        int prow = w * 16 + (lane & 15);
        short8v bfr = *(const short8v*)&w2L[prow * 128 + (kb ^ ((prow & 7) << 3))];
#pragma unroll
        for (int jt = 0; jt < 2; ++jt) {
            int jrow = jt * 16 + (lane & 15);
            short8v ah = *(const short8v*)&ahiL[jrow * 128 + (kb ^ ((jrow & 7) << 3))];
            short8v al = *(const short8v*)&aloL[jrow * 128 + (kb ^ ((jrow & 7) << 3))];
            acc2[jt] = __builtin_amdgcn_mfma_f32_16x16x32_bf16(ah, bfr, acc2[jt], 0, 0, 0);
            acc2[jt] = __builtin_amdgcn_mfma_f32_16x16x32_bf16(al, bfr, acc2[jt], 0, 0, 0);
        }
    }
    __syncthreads();  // psF/ngF visible to all

    // epilogue (r21 verbatim): wave w owns p' in [16w, 16w+16)
    int pp = w * 16 + (lane & 15);
    float u_ = uvb[pp];
    float v_ = uvb[PP + pp];
    float bb_ = uvb[2 * PP + pp];
    float w1_ = W1[pp];
    int row0 = b * NN + j0;
#pragma unroll
    for (int jt = 0; jt < 2; ++jt)
#pragma unroll
        for (int r = 0; r < 4; ++r) {
            int jloc = jt * 16 + (lane >> 4) * 4 + r;
            int row = row0 + jloc;
            float xs = x[row];
            float o = acc2[jt][r] + xs * w1_ + psF[jloc] * u_ + ngF[jloc] * v_ + bb_;
            out[(size_t)row * PP + pp] = fmaxf(o, 0.f);
        }
}

extern "C" void kernel_launch(void* const* d_in, const int* in_sizes, int n_in,
                              void* d_out, int out_size, void* d_ws, size_t ws_size,
                              hipStream_t stream) {
    const float* x      = (const float*)d_in[0];
    const float* mu     = (const float*)d_in[1];
    const float* weight = (const float*)d_in[2];
    const float* adj    = (const float*)d_in[3];
    const float* W1     = (const float*)d_in[4];
    const float* b1     = (const float*)d_in[5];
    const float* W2     = (const float*)d_in[6];
    const float* b2     = (const float*)d_in[7];
    const float* W3     = (const float*)d_in[8];
    const float* b3     = (const float*)d_in[9];
    const float* theta4 = (const float*)d_in[10];
    float* out = (float*)d_out;

    float* ws  = (float*)d_ws;
    float* uvb = ws + UVB_OFF;
    u16* muthi = (u16*)((char*)d_ws + MUTHI_OFF);
    u16* w2t   = (u16*)((char*)d_ws + W2T_OFF);

    k_aux<<<258, 256, 0, stream>>>(mu, W2, theta4, W3, b1, b2, b3, uvb,
                                   muthi, w2t);

    k_fused<<<512, 512, 0, stream>>>(adj, weight, muthi, w2t, x, W1,
                                     uvb, out);
}

// Round 24
// 35.188 us; speedup vs baseline: 1.1002x; 1.0626x over previous
//
#include <hip/hip_runtime.h>

#define BB 32
#define NN 512
#define PP 128
#define MM (BB * NN)  // 16384 rows

typedef unsigned int u32;
typedef unsigned short u16;

typedef __attribute__((ext_vector_type(8))) short short8v;  // 8 bf16 (4 VGPR)
typedef __attribute__((ext_vector_type(4))) float f32x4;

// ---- ws layout (r21/r23 verbatim) ----
#define UVB_OFF (16 * MM)               // u[128], v[128], bias[128]
#define MUTHI_OFF ((size_t)20971520)    // u16 [BB][PP][NN] = 4 MB (muT hi)
#define W2T_OFF ((size_t)29360128)      // u16 [PP][PP] = 32 KB (W2T[p][q]=bf16(W2[q][p]))

__device__ inline u32 bf16rne(float f) {
    u32 u = __float_as_uint(f);
    return (u + 0x7FFFu + ((u >> 16) & 1u)) >> 16;
}

// aux (r23 verbatim): bid<256: mu transpose -> muT bf16; 256: uv+bias;
// 257: W2T bf16.
__global__ __launch_bounds__(256) void k_aux(
    const float* __restrict__ mu, const float* __restrict__ W2,
    const float* __restrict__ t4, const float* __restrict__ W3,
    const float* __restrict__ b1, const float* __restrict__ b2,
    const float* __restrict__ b3, float* __restrict__ uvb,
    u16* __restrict__ muthi, u16* __restrict__ w2t) {
    __shared__ float tile[64][132];
    __shared__ float su[2][PP], sv[2][PP];
    int bid = blockIdx.x;
    int t = threadIdx.x;
    if (bid < 256) {
        int b = bid >> 3, i0 = (bid & 7) * 64;
        const float4* mu4 = (const float4*)(mu + ((size_t)b * NN + i0) * PP);
#pragma unroll
        for (int s = 0; s < 8; ++s) {
            int n = s * 256 + t;
            int ii = n >> 5, c4 = n & 31;
            float4 v = mu4[ii * 32 + c4];
            *(float4*)&tile[ii][c4 * 4] = v;
        }
        __syncthreads();
        int p = t >> 1, half = t & 1;
        u32* hdst = (u32*)(muthi + ((size_t)b * PP + p) * NN + i0 + half * 32);
#pragma unroll
        for (int e2 = 0; e2 < 16; ++e2) {
            float v0 = tile[half * 32 + 2 * e2][p];
            float v1 = tile[half * 32 + 2 * e2 + 1][p];
            hdst[e2] = bf16rne(v0) | (bf16rne(v1) << 16);
        }
    } else if (bid == 256) {
        int p = t & 127, h = t >> 7;
        float u = 0.f, v = 0.f;
#pragma unroll 8
        for (int q = h * 64; q < h * 64 + 64; ++q) {
            float tt = t4[q];
            float w = W3[q * PP + p];
            u += fmaxf(tt, 0.f) * w;
            v += fmaxf(-tt, 0.f) * w;
        }
        su[h][p] = u;
        sv[h][p] = v;
        __syncthreads();
        if (t < PP) {
            uvb[p] = su[0][p] + su[1][p];
            uvb[PP + p] = sv[0][p] + sv[1][p];
            uvb[2 * PP + p] = b1[p] + b2[p] + b3[p];
        }
    } else {
#pragma unroll 4
        for (int c = 0; c < 64; ++c) {
            int n = c * 256 + t;
            int q = n >> 7, pp = n & 127;
            w2t[pp * PP + q] = (u16)bf16rne(W2[q * PP + pp]);
        }
    }
}

// fused (r23 + posneg-adj-from-LDS): posneg's adj factor read from the staged
// adjL tile (symmetry: adj[i][j0+jw] == adjrow[jw][i]) — no adjcol global
// loads. Weight stays one-step-ahead register-prefetched.
// 512 blocks = 32 b x 16 j-tiles(32); 512 thr = 8 waves; wave w: p-slice 16.
__global__ __launch_bounds__(512) void k_fused(
    const float* __restrict__ adjF, const float* __restrict__ weight,
    const u16* __restrict__ muthi, const u16* __restrict__ w2t,
    const float* __restrict__ x, const float* __restrict__ W1,
    const float* __restrict__ uvb, float* __restrict__ out) {
    __shared__ __align__(16) u16 pool[24576];  // 48 KB
    // phase1 carve: adjL [32][72] @0; mhiL [128][72] @2304
    u16* adjL = pool;
    u16* mhiL = pool + 2304;
    // phase2 carve (aliases, barrier-separated): w2L [128][128 swz] @0;
    // ahiL [32][128 swz] @16384; aloL @20480
    u16* w2L = pool;
    u16* ahiL = pool + 16384;
    u16* aloL = pool + 20480;
    __shared__ float psP[16][33], ngP[16][33];  // padded
    __shared__ float psF[32], ngF[32];

    int bid = blockIdx.x;
    int vbid = ((bid & 7) << 6) | (bid >> 3);  // XCD chunking (bijective)
    int b = vbid >> 4;
    int j0 = (vbid & 15) * 32;
    int tx = threadIdx.x, lane = tx & 63, w = tx >> 6;

    const float* adjrow = adjF + ((size_t)b * NN + j0) * NN;  // [j][i] rows
    const float* wcol = weight + (size_t)b * NN * NN + j0;     // [i][j] cols
    const u16* mhG = muthi + (size_t)b * PP * NN;

    // staging maps (r23 verbatim)
    int sj = tx >> 4, sk = (tx & 15) * 4;   // adj: row sj, float4 col sk
    int sp = tx >> 2, sk2 = (tx & 3) * 16;  // mu: row sp, 2x uint4 col sk2
    const float* adjsrc = adjrow + (size_t)sj * NN + sk;
    const u16* mhsrc = mhG + (size_t)sp * NN + sk2;

    // pos/neg mapping: jw = tx&31, kgrp = tx>>5; adj factor from adjL
    int jw = tx & 31, kgrp = tx >> 5;
    float ps = 0.f, ng = 0.f;

    f32x4 acc[2];  // [jt]; wave w owns p-slice [16w, 16w+16)
    acc[0] = (f32x4){0.f, 0.f, 0.f, 0.f};
    acc[1] = (f32x4){0.f, 0.f, 0.f, 0.f};

    // ---- prologue: issue step-0 loads into registers (stage + weight) ----
    float4 fA = *(const float4*)(adjsrc);
    uint4 h0 = *(const uint4*)(mhsrc);
    uint4 h1 = *(const uint4*)(mhsrc + 8);
    float pwr[4];
#pragma unroll
    for (int kk = 0; kk < 4; ++kk)
        pwr[kk] = wcol[(size_t)(kgrp * 4 + kk) * NN + jw];

    for (int step = 0; step < 8; ++step) {
        int k0 = step * 64;
        {  // write staged regs -> LDS (adj: 0/1 -> bf16 exact)
            uint2 o;
            o.x = (fA.x != 0.f ? 0x3F80u : 0u) | (fA.y != 0.f ? 0x3F800000u : 0u);
            o.y = (fA.z != 0.f ? 0x3F80u : 0u) | (fA.w != 0.f ? 0x3F800000u : 0u);
            *(uint2*)&adjL[sj * 72 + sk] = o;
            *(uint4*)&mhiL[sp * 72 + sk2] = h0;
            *(uint4*)&mhiL[sp * 72 + sk2 + 8] = h1;
        }
        __syncthreads();
        // ---- issue NEXT-step global loads (land during MFMA + barriers) ----
        float pwn[4];
        if (step < 7) {
            int kn = k0 + 64;
            fA = *(const float4*)(adjsrc + kn);
            h0 = *(const uint4*)(mhsrc + kn);
            h1 = *(const uint4*)(mhsrc + kn + 8);
#pragma unroll
            for (int kk = 0; kk < 4; ++kk)
                pwn[kk] = wcol[(size_t)(kn + kgrp * 4 + kk) * NN + jw];
        }
        // ---- posneg: adj factor from staged adjL (symmetric tile) ----
        {
#pragma unroll
            for (int kk = 0; kk < 4; ++kk) {
                u16 av = adjL[jw * 72 + kgrp * 4 + kk];  // bf16 0x3F80 or 0
                float a = av ? 1.f : 0.f;
                ps += fmaxf(pwr[kk], 0.f) * a;
                ng += fmaxf(-pwr[kk], 0.f) * a;
            }
        }
        // ---- MFMA current step from LDS (r23 verbatim: 4 MFMA/wave) ----
#pragma unroll
        for (int ks = 0; ks < 2; ++ks) {
            int kb = ks * 32 + (lane >> 4) * 8;
            short8v afr0 = *(const short8v*)&adjL[(0 + (lane & 15)) * 72 + kb];
            short8v afr1 = *(const short8v*)&adjL[(16 + (lane & 15)) * 72 + kb];
            int prow = w * 16 + (lane & 15);
            short8v bh = *(const short8v*)&mhiL[prow * 72 + kb];
            acc[0] = __builtin_amdgcn_mfma_f32_16x16x32_bf16(afr0, bh, acc[0], 0, 0, 0);
            acc[1] = __builtin_amdgcn_mfma_f32_16x16x32_bf16(afr1, bh, acc[1], 0, 0, 0);
        }
        if (step < 7) {
#pragma unroll
            for (int kk = 0; kk < 4; ++kk) pwr[kk] = pwn[kk];
        }
        __syncthreads();
    }

    // pos/neg partials -> LDS; acc -> agg hi/lo (XOR-swz); stage W2T (r23 verbatim)
    psP[kgrp][jw] = ps;
    ngP[kgrp][jw] = ng;
    {
#pragma unroll
        for (int jt = 0; jt < 2; ++jt)
#pragma unroll
            for (int r = 0; r < 4; ++r) {
                int j = jt * 16 + (lane >> 4) * 4 + r;
                int q = w * 16 + (lane & 15);
                float v = acc[jt][r];
                u32 h = bf16rne(v);
                float lf = v - __uint_as_float(h << 16);
                int qs = q ^ ((j & 7) << 3);
                ahiL[j * 128 + qs] = (u16)h;
                aloL[j * 128 + qs] = (u16)bf16rne(lf);
            }
        int p = tx >> 2, c4 = tx & 3;
#pragma unroll
        for (int c = 0; c < 4; ++c) {
            int cc = c4 * 4 + c;
            int q8 = (cc * 8) ^ ((p & 7) << 3);
            *(uint4*)&w2L[p * 128 + q8] = *(const uint4*)(w2t + p * PP + cc * 8);
        }
    }
    __syncthreads();

    // final pos/neg reduce (32 threads)
    if (tx < 32) {
        float P = 0.f, Ng = 0.f;
#pragma unroll
        for (int g = 0; g < 16; ++g) {
            P += psP[g][tx];
            Ng += ngP[g][tx];
        }
        psF[tx] = P;
        ngF[tx] = Ng;
    }

    // phase 2 (r23 verbatim): D2[j][p'] = sum_q agg[j][q] * W2[q][p']
    f32x4 acc2[2];
    acc2[0] = (f32x4){0.f, 0.f, 0.f, 0.f};
    acc2[1] = (f32x4){0.f, 0.f, 0.f, 0.f};
#pragma unroll
    for (int ks = 0; ks < 4; ++ks) {
        int kb = ks * 32 + (lane >> 4) * 8;
        int prow = w * 16 + (lane & 15);
        short8v bfr = *(const short8v*)&w2L[prow * 128 + (kb ^ ((prow & 7) << 3))];
#pragma unroll
        for (int jt = 0; jt < 2; ++jt) {
            int jrow = jt * 16 + (lane & 15);
            short8v ah = *(const short8v*)&ahiL[jrow * 128 + (kb ^ ((jrow & 7) << 3))];
            short8v al = *(const short8v*)&aloL[jrow * 128 + (kb ^ ((jrow & 7) << 3))];
            acc2[jt] = __builtin_amdgcn_mfma_f32_16x16x32_bf16(ah, bfr, acc2[jt], 0, 0, 0);
            acc2[jt] = __builtin_amdgcn_mfma_f32_16x16x32_bf16(al, bfr, acc2[jt], 0, 0, 0);
        }
    }
    __syncthreads();  // psF/ngF visible to all

    // epilogue (r23 verbatim): wave w owns p' in [16w, 16w+16)
    int pp = w * 16 + (lane & 15);
    float u_ = uvb[pp];
    float v_ = uvb[PP + pp];
    float bb_ = uvb[2 * PP + pp];
    float w1_ = W1[pp];
    int row0 = b * NN + j0;
#pragma unroll
    for (int jt = 0; jt < 2; ++jt)
#pragma unroll
        for (int r = 0; r < 4; ++r) {
            int jloc = jt * 16 + (lane >> 4) * 4 + r;
            int row = row0 + jloc;
            float xs = x[row];
            float o = acc2[jt][r] + xs * w1_ + psF[jloc] * u_ + ngF[jloc] * v_ + bb_;
            out[(size_t)row * PP + pp] = fmaxf(o, 0.f);
        }
}

extern "C" void kernel_launch(void* const* d_in, const int* in_sizes, int n_in,
                              void* d_out, int out_size, void* d_ws, size_t ws_size,
                              hipStream_t stream) {
    const float* x      = (const float*)d_in[0];
    const float* mu     = (const float*)d_in[1];
    const float* weight = (const float*)d_in[2];
    const float* adj    = (const float*)d_in[3];
    const float* W1     = (const float*)d_in[4];
    const float* b1     = (const float*)d_in[5];
    const float* W2     = (const float*)d_in[6];
    const float* b2     = (const float*)d_in[7];
    const float* W3     = (const float*)d_in[8];
    const float* b3     = (const float*)d_in[9];
    const float* theta4 = (const float*)d_in[10];
    float* out = (float*)d_out;

    float* ws  = (float*)d_ws;
    float* uvb = ws + UVB_OFF;
    u16* muthi = (u16*)((char*)d_ws + MUTHI_OFF);
    u16* w2t   = (u16*)((char*)d_ws + W2T_OFF);

    k_aux<<<258, 256, 0, stream>>>(mu, W2, theta4, W3, b1, b2, b3, uvb,
                                   muthi, w2t);

    k_fused<<<512, 512, 0, stream>>>(adj, weight, muthi, w2t, x, W1,
                                     uvb, out);
}

// Round 25
// 34.767 us; speedup vs baseline: 1.1135x; 1.0121x over previous
//
#include <hip/hip_runtime.h>

#define BB 32
#define NN 512
#define PP 128
#define MM (BB * NN)  // 16384 rows

typedef unsigned int u32;
typedef unsigned short u16;

typedef __attribute__((ext_vector_type(8))) short short8v;  // 8 bf16 (4 VGPR)
typedef __attribute__((ext_vector_type(4))) float f32x4;

// ---- ws layout (r24 verbatim) ----
#define UVB_OFF (16 * MM)               // u[128], v[128], bias[128]
#define MUTHI_OFF ((size_t)20971520)    // u16 [BB][PP][NN] = 4 MB (muT hi)
#define W2T_OFF ((size_t)29360128)      // u16 [PP][PP] = 32 KB (W2T[p][q]=bf16(W2[q][p]))

__device__ inline u32 bf16rne(float f) {
    u32 u = __float_as_uint(f);
    return (u + 0x7FFFu + ((u >> 16) & 1u)) >> 16;
}

// aux (r24 verbatim): bid<256: mu transpose -> muT bf16; 256: uv+bias;
// 257: W2T bf16.
__global__ __launch_bounds__(256) void k_aux(
    const float* __restrict__ mu, const float* __restrict__ W2,
    const float* __restrict__ t4, const float* __restrict__ W3,
    const float* __restrict__ b1, const float* __restrict__ b2,
    const float* __restrict__ b3, float* __restrict__ uvb,
    u16* __restrict__ muthi, u16* __restrict__ w2t) {
    __shared__ float tile[64][132];
    __shared__ float su[2][PP], sv[2][PP];
    int bid = blockIdx.x;
    int t = threadIdx.x;
    if (bid < 256) {
        int b = bid >> 3, i0 = (bid & 7) * 64;
        const float4* mu4 = (const float4*)(mu + ((size_t)b * NN + i0) * PP);
#pragma unroll
        for (int s = 0; s < 8; ++s) {
            int n = s * 256 + t;
            int ii = n >> 5, c4 = n & 31;
            float4 v = mu4[ii * 32 + c4];
            *(float4*)&tile[ii][c4 * 4] = v;
        }
        __syncthreads();
        int p = t >> 1, half = t & 1;
        u32* hdst = (u32*)(muthi + ((size_t)b * PP + p) * NN + i0 + half * 32);
#pragma unroll
        for (int e2 = 0; e2 < 16; ++e2) {
            float v0 = tile[half * 32 + 2 * e2][p];
            float v1 = tile[half * 32 + 2 * e2 + 1][p];
            hdst[e2] = bf16rne(v0) | (bf16rne(v1) << 16);
        }
    } else if (bid == 256) {
        int p = t & 127, h = t >> 7;
        float u = 0.f, v = 0.f;
#pragma unroll 8
        for (int q = h * 64; q < h * 64 + 64; ++q) {
            float tt = t4[q];
            float w = W3[q * PP + p];
            u += fmaxf(tt, 0.f) * w;
            v += fmaxf(-tt, 0.f) * w;
        }
        su[h][p] = u;
        sv[h][p] = v;
        __syncthreads();
        if (t < PP) {
            uvb[p] = su[0][p] + su[1][p];
            uvb[PP + p] = sv[0][p] + sv[1][p];
            uvb[2 * PP + p] = b1[p] + b2[p] + b3[p];
        }
    } else {
#pragma unroll 4
        for (int c = 0; c < 64; ++c) {
            int n = c * 256 + t;
            int q = n >> 7, pp = n & 127;
            w2t[pp * PP + q] = (u16)bf16rne(W2[q * PP + pp]);
        }
    }
}

// fused (r24 + LDS double-buffer, ONE barrier per step):
// even steps use bufA, odd use bufB; write step s+1 into its buffer while
// MFMA reads step s's. 9 barriers total (was 16). Manually unrolled by 2
// with named register sets (static access, rule #20).
// 512 blocks = 32 b x 16 j-tiles(32); 512 thr = 8 waves; wave w: p-slice 16.
__global__ __launch_bounds__(512) void k_fused(
    const float* __restrict__ adjF, const float* __restrict__ weight,
    const u16* __restrict__ muthi, const u16* __restrict__ w2t,
    const float* __restrict__ x, const float* __restrict__ W1,
    const float* __restrict__ uvb, float* __restrict__ out) {
    __shared__ __align__(16) u16 pool[24576];  // 48 KB
    // phase1 dbuf carve: bufA: adjL @0, mhiL @2304 | bufB: adjL @11520, mhiL @13824
    u16* adjA = pool;
    u16* mhiA = pool + 2304;
    u16* adjB = pool + 11520;
    u16* mhiB = pool + 13824;
    // phase2 carve (aliases, barrier-separated): w2L [128][128 swz] @0;
    // ahiL [32][128 swz] @16384; aloL @20480
    u16* w2L = pool;
    u16* ahiL = pool + 16384;
    u16* aloL = pool + 20480;
    __shared__ float psP[16][33], ngP[16][33];  // padded
    __shared__ float psF[32], ngF[32];

    int bid = blockIdx.x;
    int vbid = ((bid & 7) << 6) | (bid >> 3);  // XCD chunking (bijective)
    int b = vbid >> 4;
    int j0 = (vbid & 15) * 32;
    int tx = threadIdx.x, lane = tx & 63, w = tx >> 6;

    const float* adjrow = adjF + ((size_t)b * NN + j0) * NN;  // [j][i] rows
    const float* wcol = weight + (size_t)b * NN * NN + j0;     // [i][j] cols
    const u16* mhG = muthi + (size_t)b * PP * NN;

    // staging maps (r24 verbatim)
    int sj = tx >> 4, sk = (tx & 15) * 4;   // adj: row sj, float4 col sk
    int sp = tx >> 2, sk2 = (tx & 3) * 16;  // mu: row sp, 2x uint4 col sk2
    const float* adjsrc = adjrow + (size_t)sj * NN + sk;
    const u16* mhsrc = mhG + (size_t)sp * NN + sk2;

    // pos/neg mapping (r24 verbatim): jw = tx&31, kgrp = tx>>5
    int jw = tx & 31, kgrp = tx >> 5;
    float ps = 0.f, ng = 0.f;

    f32x4 acc[2];  // [jt]; wave w owns p-slice [16w, 16w+16)
    acc[0] = (f32x4){0.f, 0.f, 0.f, 0.f};
    acc[1] = (f32x4){0.f, 0.f, 0.f, 0.f};

#define STAGE_WRITE(ADJ, MHI, fa, H0, H1)                                      \
    {                                                                          \
        uint2 o;                                                               \
        o.x = (fa.x != 0.f ? 0x3F80u : 0u) | (fa.y != 0.f ? 0x3F800000u : 0u); \
        o.y = (fa.z != 0.f ? 0x3F80u : 0u) | (fa.w != 0.f ? 0x3F800000u : 0u); \
        *(uint2*)&ADJ[sj * 72 + sk] = o;                                       \
        *(uint4*)&MHI[sp * 72 + sk2] = H0;                                     \
        *(uint4*)&MHI[sp * 72 + sk2 + 8] = H1;                                 \
    }

#define POSNEG(ADJ, PW)                                                        \
    {                                                                          \
        _Pragma("unroll") for (int kk = 0; kk < 4; ++kk) {                     \
            u16 av = ADJ[jw * 72 + kgrp * 4 + kk];                             \
            float a = av ? 1.f : 0.f;                                          \
            ps += fmaxf(PW[kk], 0.f) * a;                                      \
            ng += fmaxf(-PW[kk], 0.f) * a;                                     \
        }                                                                      \
    }

#define MFMA_STEP(ADJ, MHI)                                                    \
    {                                                                          \
        _Pragma("unroll") for (int ks = 0; ks < 2; ++ks) {                     \
            int kb = ks * 32 + (lane >> 4) * 8;                                \
            short8v afr0 = *(const short8v*)&ADJ[(0 + (lane & 15)) * 72 + kb]; \
            short8v afr1 = *(const short8v*)&ADJ[(16 + (lane & 15)) * 72 + kb];\
            int prow = w * 16 + (lane & 15);                                   \
            short8v bh = *(const short8v*)&MHI[prow * 72 + kb];                \
            acc[0] = __builtin_amdgcn_mfma_f32_16x16x32_bf16(afr0, bh, acc[0], 0, 0, 0); \
            acc[1] = __builtin_amdgcn_mfma_f32_16x16x32_bf16(afr1, bh, acc[1], 0, 0, 0); \
        }                                                                      \
    }

    // ---- prologue: load+write step0 (bufA); load step1 regs (set B) ----
    float4 fA_a = *(const float4*)(adjsrc);
    uint4 h0_a = *(const uint4*)(mhsrc);
    uint4 h1_a = *(const uint4*)(mhsrc + 8);
    float pw_a[4], pw_b[4];
#pragma unroll
    for (int kk = 0; kk < 4; ++kk)
        pw_a[kk] = wcol[(size_t)(kgrp * 4 + kk) * NN + jw];
    STAGE_WRITE(adjA, mhiA, fA_a, h0_a, h1_a);
    float4 fA_b = *(const float4*)(adjsrc + 64);
    uint4 h0_b = *(const uint4*)(mhsrc + 64);
    uint4 h1_b = *(const uint4*)(mhsrc + 72);
#pragma unroll
    for (int kk = 0; kk < 4; ++kk)
        pw_b[kk] = wcol[(size_t)(64 + kgrp * 4 + kk) * NN + jw];
    __syncthreads();  // bufA ready

    for (int it = 0; it < 4; ++it) {
        int k0 = it * 128;
        // ---- EVEN step s=2it (bufA) ----
        if (it < 3) {  // issue step s+2 into set A (regs free: written last odd body)
            int kn = k0 + 128;
            fA_a = *(const float4*)(adjsrc + kn);
            h0_a = *(const uint4*)(mhsrc + kn);
            h1_a = *(const uint4*)(mhsrc + kn + 8);
        }
        POSNEG(adjA, pw_a);
        if (it < 3) {
            int kn = k0 + 128;
#pragma unroll
            for (int kk = 0; kk < 4; ++kk)
                pw_a[kk] = wcol[(size_t)(kn + kgrp * 4 + kk) * NN + jw];
        }
        MFMA_STEP(adjA, mhiA);
        STAGE_WRITE(adjB, mhiB, fA_b, h0_b, h1_b);  // step s+1 (bufB safe: readers done at last barrier)
        __syncthreads();  // bufB ready; bufA readers done
        // ---- ODD step s=2it+1 (bufB) ----
        if (it < 3) {  // issue step s+2 into set B
            int kn = k0 + 192;
            fA_b = *(const float4*)(adjsrc + kn);
            h0_b = *(const uint4*)(mhsrc + kn);
            h1_b = *(const uint4*)(mhsrc + kn + 8);
        }
        POSNEG(adjB, pw_b);
        if (it < 3) {
            int kn = k0 + 192;
#pragma unroll
            for (int kk = 0; kk < 4; ++kk)
                pw_b[kk] = wcol[(size_t)(kn + kgrp * 4 + kk) * NN + jw];
        }
        MFMA_STEP(adjB, mhiB);
        if (it < 3) STAGE_WRITE(adjA, mhiA, fA_a, h0_a, h1_a);  // step s+2 into bufA
        __syncthreads();  // bufA ready (or final: phase-1 pool dead)
    }

    // pos/neg partials -> LDS; acc -> agg hi/lo (XOR-swz); stage W2T (r24 verbatim)
    psP[kgrp][jw] = ps;
    ngP[kgrp][jw] = ng;
    {
#pragma unroll
        for (int jt = 0; jt < 2; ++jt)
#pragma unroll
            for (int r = 0; r < 4; ++r) {
                int j = jt * 16 + (lane >> 4) * 4 + r;
                int q = w * 16 + (lane & 15);
                float v = acc[jt][r];
                u32 h = bf16rne(v);
                float lf = v - __uint_as_float(h << 16);
                int qs = q ^ ((j & 7) << 3);
                ahiL[j * 128 + qs] = (u16)h;
                aloL[j * 128 + qs] = (u16)bf16rne(lf);
            }
        int p = tx >> 2, c4 = tx & 3;
#pragma unroll
        for (int c = 0; c < 4; ++c) {
            int cc = c4 * 4 + c;
            int q8 = (cc * 8) ^ ((p & 7) << 3);
            *(uint4*)&w2L[p * 128 + q8] = *(const uint4*)(w2t + p * PP + cc * 8);
        }
    }
    __syncthreads();

    // final pos/neg reduce (32 threads)
    if (tx < 32) {
        float P = 0.f, Ng = 0.f;
#pragma unroll
        for (int g = 0; g < 16; ++g) {
            P += psP[g][tx];
            Ng += ngP[g][tx];
        }
        psF[tx] = P;
        ngF[tx] = Ng;
    }

    // phase 2 (r24 verbatim): D2[j][p'] = sum_q agg[j][q] * W2[q][p']
    f32x4 acc2[2];
    acc2[0] = (f32x4){0.f, 0.f, 0.f, 0.f};
    acc2[1] = (f32x4){0.f, 0.f, 0.f, 0.f};
#pragma unroll
    for (int ks = 0; ks < 4; ++ks) {
        int kb = ks * 32 + (lane >> 4) * 8;
        int prow = w * 16 + (lane & 15);
        short8v bfr = *(const short8v*)&w2L[prow * 128 + (kb ^ ((prow & 7) << 3))];
#pragma unroll
        for (int jt = 0; jt < 2; ++jt) {
            int jrow = jt * 16 + (lane & 15);
            short8v ah = *(const short8v*)&ahiL[jrow * 128 + (kb ^ ((jrow & 7) << 3))];
            short8v al = *(const short8v*)&aloL[jrow * 128 + (kb ^ ((jrow & 7) << 3))];
            acc2[jt] = __builtin_amdgcn_mfma_f32_16x16x32_bf16(ah, bfr, acc2[jt], 0, 0, 0);
            acc2[jt] = __builtin_amdgcn_mfma_f32_16x16x32_bf16(al, bfr, acc2[jt], 0, 0, 0);
        }
    }
    __syncthreads();  // psF/ngF visible to all

    // epilogue (r24 verbatim): wave w owns p' in [16w, 16w+16)
    int pp = w * 16 + (lane & 15);
    float u_ = uvb[pp];
    float v_ = uvb[PP + pp];
    float bb_ = uvb[2 * PP + pp];
    float w1_ = W1[pp];
    int row0 = b * NN + j0;
#pragma unroll
    for (int jt = 0; jt < 2; ++jt)
#pragma unroll
        for (int r = 0; r < 4; ++r) {
            int jloc = jt * 16 + (lane >> 4) * 4 + r;
            int row = row0 + jloc;
            float xs = x[row];
            float o = acc2[jt][r] + xs * w1_ + psF[jloc] * u_ + ngF[jloc] * v_ + bb_;
            out[(size_t)row * PP + pp] = fmaxf(o, 0.f);
        }
}

extern "C" void kernel_launch(void* const* d_in, const int* in_sizes, int n_in,
                              void* d_out, int out_size, void* d_ws, size_t ws_size,
                              hipStream_t stream) {
    const float* x      = (const float*)d_in[0];
    const float* mu     = (const float*)d_in[1];
    const float* weight = (const float*)d_in[2];
    const float* adj    = (const float*)d_in[3];
    const float* W1     = (const float*)d_in[4];
    const float* b1     = (const float*)d_in[5];
    const float* W2     = (const float*)d_in[6];
    const float* b2     = (const float*)d_in[7];
    const float* W3     = (const float*)d_in[8];
    const float* b3     = (const float*)d_in[9];
    const float* theta4 = (const float*)d_in[10];
    float* out = (float*)d_out;

    float* ws  = (float*)d_ws;
    float* uvb = ws + UVB_OFF;
    u16* muthi = (u16*)((char*)d_ws + MUTHI_OFF);
    u16* w2t   = (u16*)((char*)d_ws + W2T_OFF);

    k_aux<<<258, 256, 0, stream>>>(mu, W2, theta4, W3, b1, b2, b3, uvb,
                                   muthi, w2t);

    k_fused<<<512, 512, 0, stream>>>(adj, weight, muthi, w2t, x, W1,
                                     uvb, out);
}